// Round 5
// baseline (55.727 us; speedup 1.0000x reference)
//
#include <hip/hip_runtime.h>
#include <hip/hip_bf16.h>
#include <math.h>

#define B   8
#define S   64
#define NL  128
#define NPRO 256
#define NN  384   // NL + NPRO
#define P   64
#define NGRP 8
#define EPSF 1e-6f

// ---------------------------------------------------------------------------
// Kernel 1: mean_len[b,s]
// ---------------------------------------------------------------------------
__global__ __launch_bounds__(64) void meanlen_kernel(
    const float* __restrict__ lig, const float* __restrict__ ligmask,
    const float* __restrict__ pro, const float* __restrict__ promask,
    float* __restrict__ meanlen)
{
    int blk = blockIdx.x;              // b*S + s
    int t = threadIdx.x;
    float suml = 0.f, cnt = 0.f;

    const float* lbase = lig + (size_t)blk * NL * 3;
    const float* lm    = ligmask + (size_t)blk * NL;
    for (int n = t; n < NL; n += 64) {
        float x = lbase[n*3+0], y = lbase[n*3+1], z = lbase[n*3+2];
        float mk = lm[n];
        suml += sqrtf(x*x + y*y + z*z) * mk;
        cnt  += mk;
    }
    const float* pbase = pro + (size_t)blk * NPRO * 3;
    const float* pm    = promask + (size_t)blk * NPRO;
    for (int n = t; n < NPRO; n += 64) {
        float x = pbase[n*3+0], y = pbase[n*3+1], z = pbase[n*3+2];
        float mk = pm[n];
        suml += sqrtf(x*x + y*y + z*z) * mk;
        cnt  += mk;
    }
    for (int off = 32; off > 0; off >>= 1) {
        suml += __shfl_down(suml, off);
        cnt  += __shfl_down(cnt,  off);
    }
    if (t == 0) meanlen[blk] = suml / cnt;
}

// ---------------------------------------------------------------------------
// Kernel 2: SoA projection planes
// projc[b,n,p] = sum_s coord[b,s,n,c] * sw[s]/(mean+eps)*mask * w[p,s]
// ---------------------------------------------------------------------------
__global__ __launch_bounds__(64) void proj_kernel(
    const float* __restrict__ lig, const float* __restrict__ pro,
    const float* __restrict__ ligmask, const float* __restrict__ promask,
    const float* __restrict__ ligw, const float* __restrict__ prow,
    const float* __restrict__ sw, const float* __restrict__ meanlen,
    float* __restrict__ projx, float* __restrict__ projy, float* __restrict__ projz)
{
    int blk = blockIdx.x;
    int b = blk / (NN / NGRP);
    int g = blk - b * (NN / NGRP);
    int nbase = g * NGRP;
    int t = threadIdx.x;
    bool isl = (nbase < NL);

    __shared__ float wl[64][65];           // wl[p][s], padded
    const float* w = isl ? ligw : prow;    // (P,S)
    for (int row = 0; row < 64; ++row) wl[row][t] = w[row * 64 + t];

    __shared__ float cs[NGRP][3][64];      // coords premultiplied by g-factor
    {
        int s = t;
        float gfac = sw[s] / (meanlen[b * S + s] + EPSF);
        for (int nn = 0; nn < NGRP; ++nn) {
            int n = nbase + nn;
            float mk, X, Y, Z;
            if (isl) {
                size_t base = ((size_t)b * S + s) * NL + n;
                mk = ligmask[base];
                X = lig[base*3+0]; Y = lig[base*3+1]; Z = lig[base*3+2];
            } else {
                size_t base = ((size_t)b * S + s) * NPRO + (n - NL);
                mk = promask[base];
                X = pro[base*3+0]; Y = pro[base*3+1]; Z = pro[base*3+2];
            }
            float gg = gfac * mk;
            cs[nn][0][s] = X * gg;
            cs[nn][1][s] = Y * gg;
            cs[nn][2][s] = Z * gg;
        }
    }
    __syncthreads();

    for (int nn = 0; nn < NGRP; ++nn) {
        float a0 = 0.f, a1 = 0.f, a2 = 0.f;
        #pragma unroll 8
        for (int s = 0; s < 64; ++s) {
            float wv = wl[t][s];
            a0 += cs[nn][0][s] * wv;
            a1 += cs[nn][1][s] * wv;
            a2 += cs[nn][2][s] * wv;
        }
        size_t base = ((size_t)b * NN + nbase + nn) * P;
        projx[base + t] = a0;
        projy[base + t] = a1;
        projz[base + t] = a2;
    }
}

// ---------------------------------------------------------------------------
// Kernel 3 (dominant): messages staged via global_load_lds (fire-and-forget
// DMA, no VGPR round-trip) with double-buffered LDS tiles of 32 n-rows;
// 2-phase schedule: STAGE(next) -> consume(cur) -> barrier. proj planes are
// L2-hot direct loads. grid = B*NL blocks of 256 threads (4 waves).
// Thread: pg = t&15 -> 4 consecutive p; sub = t>>4 -> rows {2*sub, 2*sub+1}
// of the 32-row tile.
// ---------------------------------------------------------------------------
#define NTILE 32
#define TILES (NN / NTILE)   // 12

#define PROC(mm, am, xx, yy, zz, C) { \
    float d0 = xix.C - xx.C, d1 = xiy.C - yy.C, d2 = xiz.C - zz.C; \
    float sq = fmaf(d0, d0, fmaf(d1, d1, d2 * d2)); \
    float inv; asm("v_rsq_f32 %0, %1" : "=v"(inv) : "v"(sq)); \
    inv = fminf(inv, 1e30f); \
    float xe = fmaf(mm.C, 1.44269504f, am); \
    float e; asm("v_exp_f32 %0, %1" : "=v"(e) : "v"(xe)); \
    S1.C += e; S2.C = fmaf(e, e, S2.C); \
    float ei = e * inv; \
    A0.C = fmaf(ei, d0, A0.C); A1.C = fmaf(ei, d1, A1.C); A2.C = fmaf(ei, d2, A2.C); }

#define RED(V) { V.x += __shfl_xor(V.x, off); V.y += __shfl_xor(V.y, off); \
                 V.z += __shfl_xor(V.z, off); V.w += __shfl_xor(V.w, off); }

__global__ __launch_bounds__(256) void attn_kernel(
    const float* __restrict__ messages,   // (B, NL, NN, P)
    const int*   __restrict__ adj,        // (B, NL, NN)
    const float* __restrict__ projx,      // (B, NN, P)
    const float* __restrict__ projy,
    const float* __restrict__ projz,
    const float* __restrict__ attn_w,     // (S, P)
    float* __restrict__ out)              // (B, S, NL, 3)
{
    int blk = blockIdx.x;        // b*NL + i
    int b = blk >> 7;
    int i = blk & (NL - 1);
    int t = threadIdx.x;
    int lane = t & 63;
    int wave = t >> 6;           // 0..3
    int pg  = t & 15;            // p-group: p = pg*4 .. pg*4+3
    int sub = t >> 4;            // 0..15 -> tile rows {2*sub, 2*sub+1}
    int wsl = lane >> 4;         // 0..3 (reduction partner bits)

    __shared__ float amask[NN];
    __shared__ __align__(16) float msgT[2][NTILE * P];   // 2 x 8 KB
    __shared__ __align__(16) float red[4][5][64];
    __shared__ float upd[3][64];

    const int* adjb = adj + (size_t)blk * NN;
    for (int n = t; n < NN; n += 256)
        amask[n] = adjb[n] > 0 ? 0.f : -INFINITY;

    const float* msgb = messages + (size_t)blk * NN * P;
    const float4* px4 = (const float4*)projx + (size_t)b * NN * 16;
    const float4* py4 = (const float4*)projy + (size_t)b * NN * 16;
    const float4* pz4 = (const float4*)projz + (size_t)b * NN * 16;

    float4 xix = px4[(size_t)i * 16 + pg];
    float4 xiy = py4[(size_t)i * 16 + pg];
    float4 xiz = pz4[(size_t)i * 16 + pg];

    // fire-and-forget DMA: 2 x 16B per thread per tile (8 KB tile)
    // LDS dst = wave-uniform base (+ HW lane*16); global src = per-lane.
    #define STAGE(buf, tile) { \
        const char* gs = (const char*)(msgb + (size_t)(tile) * (NTILE * P)); \
        char* ls = (char*)&msgT[buf][0] + wave * 2048; \
        unsigned lo = wave * 2048 + lane * 16; \
        __builtin_amdgcn_global_load_lds((const unsigned int*)(gs + lo), \
                                         (unsigned int*)ls, 16, 0, 0); \
        __builtin_amdgcn_global_load_lds((const unsigned int*)(gs + lo + 1024), \
                                         (unsigned int*)(ls + 1024), 16, 0, 0); \
    }

    STAGE(0, 0)
    __syncthreads();   // amask + tile 0 ready

    float4 S1 = {0,0,0,0}, S2 = {0,0,0,0};
    float4 A0 = {0,0,0,0}, A1 = {0,0,0,0}, A2 = {0,0,0,0};

    int cur = 0;
    #pragma unroll
    for (int tile = 0; tile < TILES; ++tile) {
        if (tile < TILES - 1) STAGE(cur ^ 1, tile + 1)

        int n0 = tile * NTILE + sub * 2;
        float4 mA = *(const float4*)&msgT[cur][(sub * 2    ) * P + pg * 4];
        float4 mB = *(const float4*)&msgT[cur][(sub * 2 + 1) * P + pg * 4];
        float amA = amask[n0], amB = amask[n0 + 1];

        size_t gA = (size_t)n0 * 16 + pg;
        float4 xA = px4[gA],      yA = py4[gA],      zA = pz4[gA];
        float4 xB = px4[gA + 16], yB = py4[gA + 16], zB = pz4[gA + 16];

        PROC(mA, amA, xA, yA, zA, x) PROC(mA, amA, xA, yA, zA, y)
        PROC(mA, amA, xA, yA, zA, z) PROC(mA, amA, xA, yA, zA, w)
        PROC(mB, amB, xB, yB, zB, x) PROC(mB, amB, xB, yB, zB, y)
        PROC(mB, amB, xB, yB, zB, z) PROC(mB, amB, xB, yB, zB, w)

        __syncthreads();   // stage(next) complete; all waves done reading cur
        cur ^= 1;
    }

    // reduce across sub within wave (lane bits 4,5), then across 4 waves
    #pragma unroll
    for (int off = 16; off <= 32; off <<= 1) {
        RED(S1) RED(S2) RED(A0) RED(A1) RED(A2)
    }

    if (wsl == 0) {    // lanes 0..15 hold per-wave partial at pg
        int pb = pg * 4;
        *(float4*)&red[wave][0][pb] = S1; *(float4*)&red[wave][1][pb] = S2;
        *(float4*)&red[wave][2][pb] = A0; *(float4*)&red[wave][3][pb] = A1;
        *(float4*)&red[wave][4][pb] = A2;
    }
    __syncthreads();

    if (t < 64) {
        float s1 = 0.f, s2 = 0.f, a0 = 0.f, a1 = 0.f, a2 = 0.f;
        #pragma unroll
        for (int w = 0; w < 4; ++w) {
            s1 += red[w][0][t]; s2 += red[w][1][t];
            a0 += red[w][2][t]; a1 += red[w][3][t]; a2 += red[w][4][t];
        }
        float wgt = sqrtf(s2) / (s1 * s1);   // (A/S1)*sqrt(S2)/S1
        upd[0][t] = a0 * wgt;
        upd[1][t] = a1 * wgt;
        upd[2][t] = a2 * wgt;
    }
    __syncthreads();

    // out[b,s,i,c] = sum_p upd[c][p] * attn_w[s,p]; t<192: s=t&63, c=t>>6
    if (t < 192) {
        int s = t & 63, c = t >> 6;
        const float4* aw4 = (const float4*)attn_w + (size_t)s * 16;
        float o = 0.f;
        #pragma unroll
        for (int q = 0; q < 16; ++q) {
            float4 w4 = aw4[q];
            o = fmaf(upd[c][q*4+0], w4.x, o);
            o = fmaf(upd[c][q*4+1], w4.y, o);
            o = fmaf(upd[c][q*4+2], w4.z, o);
            o = fmaf(upd[c][q*4+3], w4.w, o);
        }
        out[(((size_t)b * S + s) * NL + i) * 3 + c] = o;
    }
}

extern "C" void kernel_launch(void* const* d_in, const int* in_sizes, int n_in,
                              void* d_out, int out_size, void* d_ws, size_t ws_size,
                              hipStream_t stream)
{
    const float* lig      = (const float*)d_in[0];   // (B,S,NL,3)
    const float* messages = (const float*)d_in[1];   // (B,NL,NN,P)
    const int*   adj      = (const int*)  d_in[2];   // (B,NL,NN)
    const float* ligmask  = (const float*)d_in[3];   // (B,S,NL)
    const float* pro      = (const float*)d_in[4];   // (B,S,NPRO,3)
    const float* promask  = (const float*)d_in[5];   // (B,S,NPRO)
    const float* ligw     = (const float*)d_in[6];   // (P,S)
    const float* prow     = (const float*)d_in[7];   // (P,S)
    const float* attnw    = (const float*)d_in[8];   // (S,P)
    const float* sw       = (const float*)d_in[9];   // (S,)
    float* out = (float*)d_out;

    const size_t plane = (size_t)B * NN * P;         // 196608 floats
    float* meanlen = (float*)d_ws;                               // 2 KB
    float* projx   = (float*)((char*)d_ws + 2048);
    float* projy   = projx + plane;
    float* projz   = projy + plane;

    meanlen_kernel<<<B * S, 64, 0, stream>>>(lig, ligmask, pro, promask, meanlen);
    proj_kernel<<<B * (NN / NGRP), 64, 0, stream>>>(lig, pro, ligmask, promask,
                                                    ligw, prow, sw, meanlen,
                                                    projx, projy, projz);
    attn_kernel<<<B * NL, 256, 0, stream>>>(messages, adj, projx, projy, projz,
                                            attnw, out);
}